// Round 8
// baseline (368.870 us; speedup 1.0000x reference)
//
#include <hip/hip_runtime.h>
#include <stdint.h>

#define D_MODEL 1024
#define S_LEN   2048
#define BATCH   2
#define NHEAD   16
#define DHEAD   64
#define NTOK    (BATCH * S_LEN)   // 4096

typedef unsigned short u16;
typedef __attribute__((ext_vector_type(8))) short bf16x8;
typedef __attribute__((ext_vector_type(4))) float f32x4;
typedef __attribute__((ext_vector_type(16))) float f32x16;
typedef __attribute__((ext_vector_type(2))) unsigned int u32x2;

__device__ __forceinline__ unsigned pack2bf(float lo, float hi) {
    unsigned a = __float_as_uint(lo) + 0x8000u;
    unsigned b = __float_as_uint(hi) + 0x8000u;
    return __builtin_amdgcn_perm(b, a, 0x07060302u);  // lo16=bf16(lo), hi16=bf16(hi)
}
__device__ __forceinline__ u16 f2bf1(float f) {
    return (u16)((__float_as_uint(f) + 0x8000u) >> 16);
}

#define GAS(p) ((const __attribute__((address_space(1))) void*)(p))
#define LAS(p) ((__attribute__((address_space(3))) void*)(p))
// chunk-XOR swizzled flat [rows][64] bf16 tile: u16 index of (row, chunk-col c)
#define SWZ8(row, c) (((((row) << 3) | ((c) ^ ((row) & 7)))) << 3)

// ---------------------------------------------------------------------------
// convert: fp32 -> bf16 for Q,K,V (4M each) and Wq,Wk,Wv,Wo (1M each).
// ---------------------------------------------------------------------------
__global__ __launch_bounds__(256) void convert_kernel(
    const float* __restrict__ Q, const float* __restrict__ K, const float* __restrict__ V,
    const float* __restrict__ Wq, const float* __restrict__ Wk,
    const float* __restrict__ Wv, const float* __restrict__ Wo,
    u16* __restrict__ Qb, u16* __restrict__ Kb, u16* __restrict__ Vb,
    u16* __restrict__ Wqb, u16* __restrict__ Wkb, u16* __restrict__ Wvb, u16* __restrict__ Wob)
{
    const size_t SEG = 262144;  // float4 per 1M-float quarter
    size_t start = (size_t)blockIdx.x * 4096;
    int s = (int)(start / SEG);
    const float* src; u16* dst; size_t seg0;
    if (s < 4)       { src = Q;  dst = Qb;  seg0 = 0; }
    else if (s < 8)  { src = K;  dst = Kb;  seg0 = 4 * SEG; }
    else if (s < 12) { src = V;  dst = Vb;  seg0 = 8 * SEG; }
    else if (s == 12){ src = Wq; dst = Wqb; seg0 = 12 * SEG; }
    else if (s == 13){ src = Wk; dst = Wkb; seg0 = 13 * SEG; }
    else if (s == 14){ src = Wv; dst = Wvb; seg0 = 14 * SEG; }
    else             { src = Wo; dst = Wob; seg0 = 15 * SEG; }
    size_t off = start - seg0 + threadIdx.x;
    const float4* s4 = (const float4*)src;
    #pragma unroll
    for (int k = 0; k < 16; ++k) {
        float4 x = s4[off + (size_t)k * 256];
        u32x2 p = (u32x2){pack2bf(x.x, x.y), pack2bf(x.z, x.w)};
        *(u32x2*)(dst + (off + (size_t)k * 256) * 4) = p;
    }
}

// ---------------------------------------------------------------------------
// proj: all three projections, ONE launch (grid 256 x 3 = 768, 3 blocks/CU).
// Operand-swapped: A = W (m = dout), B = X (n = token).
//  z=0: qw[tok][dm] = (Qb@Wq^T + bq) * 0.125*log2(e)
//  z=1: kw[tok][dm] =  Kb@Wk^T + bk
//  z=2: vtw[dout][tok] = Wv@Vb^T + bv   (kv-contiguous rows for attention)
// ---------------------------------------------------------------------------
__global__ __launch_bounds__(256) void proj_kernel(
    const u16* __restrict__ Qb, const u16* __restrict__ Kb, const u16* __restrict__ Vb,
    const u16* __restrict__ Wqb, const u16* __restrict__ Wkb, const u16* __restrict__ Wvb,
    const float* __restrict__ bq, const float* __restrict__ bk, const float* __restrict__ bv,
    u16* __restrict__ qw, u16* __restrict__ kw, u16* __restrict__ vtw)
{
    const int z = blockIdx.z;
    const int bx = blockIdx.x;
    const u16* A = (z == 0) ? Wqb : (z == 1) ? Wkb : Wvb;   // [dout][din]
    const u16* B = (z == 0) ? Qb  : (z == 1) ? Kb  : Vb;    // [tok][din]
    const float* bias = (z == 0) ? bq : (z == 1) ? bk : bv; // indexed by dout
    const int mbase = (bx & 7) * 128;    // dout
    const int nbase = (bx >> 3) * 128;   // token

    const int tid = threadIdx.x, lane = tid & 63, wave = tid >> 6;
    const int m16 = lane & 15, quad = lane >> 4;
    const int wm = wave >> 1, wn = wave & 1;

    __shared__ __align__(16) u16 As[128 * 64];
    __shared__ __align__(16) u16 Bs[128 * 64];

    int srow[4], scg[4];
    #pragma unroll
    for (int c = 0; c < 4; ++c) {
        int p = (wave * 4 + c) * 64 + lane;
        srow[c] = p >> 3;
        scg[c]  = (p & 7) ^ (srow[c] & 7);
    }

    f32x4 acc[4][4];
    #pragma unroll
    for (int mt = 0; mt < 4; ++mt)
        #pragma unroll
        for (int nt = 0; nt < 4; ++nt) acc[mt][nt] = (f32x4){0.f, 0.f, 0.f, 0.f};

    for (int kc = 0; kc < D_MODEL; kc += 64) {
        #pragma unroll
        for (int c = 0; c < 4; ++c) {
            __builtin_amdgcn_global_load_lds(
                GAS(A + (size_t)(mbase + srow[c]) * D_MODEL + kc + scg[c] * 8),
                LAS(As + (wave * 4 + c) * 512), 16, 0, 0);
            __builtin_amdgcn_global_load_lds(
                GAS(B + (size_t)(nbase + srow[c]) * D_MODEL + kc + scg[c] * 8),
                LAS(Bs + (wave * 4 + c) * 512), 16, 0, 0);
        }
        __syncthreads();
        #pragma unroll
        for (int half = 0; half < 2; ++half) {
            bf16x8 af[4], bfr[4];
            #pragma unroll
            for (int mt = 0; mt < 4; ++mt)
                af[mt] = *(const bf16x8*)&As[SWZ8(wm * 64 + mt * 16 + m16, quad + 4 * half)];
            #pragma unroll
            for (int nt = 0; nt < 4; ++nt)
                bfr[nt] = *(const bf16x8*)&Bs[SWZ8(wn * 64 + nt * 16 + m16, quad + 4 * half)];
            #pragma unroll
            for (int mt = 0; mt < 4; ++mt)
                #pragma unroll
                for (int nt = 0; nt < 4; ++nt)
                    acc[mt][nt] = __builtin_amdgcn_mfma_f32_16x16x32_bf16(af[mt], bfr[nt], acc[mt][nt], 0, 0, 0);
        }
        __syncthreads();
    }

    if (z < 2) {
        u16* Y = z ? kw : qw;
        const float scale = z ? 1.0f : 0.18033688011112042f;  // 0.125*log2(e)
        #pragma unroll
        for (int mt = 0; mt < 4; ++mt) {
            int d0 = mbase + wm * 64 + mt * 16 + quad * 4;
            float4 b4 = *(const float4*)&bias[d0];
            #pragma unroll
            for (int nt = 0; nt < 4; ++nt) {
                int tok = nbase + wn * 64 + nt * 16 + m16;
                float v0 = (acc[mt][nt][0] + b4.x) * scale;
                float v1 = (acc[mt][nt][1] + b4.y) * scale;
                float v2 = (acc[mt][nt][2] + b4.z) * scale;
                float v3 = (acc[mt][nt][3] + b4.w) * scale;
                *(u32x2*)(Y + (size_t)tok * D_MODEL + d0) =
                    (u32x2){pack2bf(v0, v1), pack2bf(v2, v3)};
            }
        }
    } else {
        #pragma unroll
        for (int mt = 0; mt < 4; ++mt)
            #pragma unroll
            for (int r = 0; r < 4; ++r) {
                int dout = mbase + wm * 64 + mt * 16 + quad * 4 + r;
                float bb = bias[dout];
                #pragma unroll
                for (int nt = 0; nt < 4; ++nt) {
                    int tok = nbase + wn * 64 + nt * 16 + m16;
                    vtw[(size_t)dout * NTOK + tok] = f2bf1(acc[mt][nt][r] + bb);
                }
            }
    }
}

// ---------------------------------------------------------------------------
// Flash attention, kv-split x2 for full occupancy: grid (16,16,4) = 1024
// blocks of 512 thr = 4 blocks/CU = 32 waves/CU. blockIdx.z = b*2 + half;
// each block sums kv in [half*1024, half*1024+1024). Blocks write
// UNNORMALIZED bf16 O-partials + fp32 l-partials; merge_kernel combines.
// 8 waves = 4 q-tiles(32q) x 2 kv-quarter-waves. Fixed-max exp2 softmax.
// ---------------------------------------------------------------------------
__global__ __launch_bounds__(512, 8) void attn_kernel(
    const u16* __restrict__ qw, const u16* __restrict__ kw,
    const u16* __restrict__ vtw, u16* __restrict__ op, float* __restrict__ lp)
{
    const int qbase = blockIdx.x * 128;
    const int h = blockIdx.y;
    const int b    = blockIdx.z >> 1;
    const int half = blockIdx.z & 1;
    const int tid = threadIdx.x, lane = tid & 63, wave = tid >> 6;
    const int wq = wave & 3;        // q-tile (32 q rows)
    const int wk = wave >> 2;       // kv half of the 64-tile
    const int l31 = lane & 31;
    const int hh  = lane >> 5;
    const int colbase = h * DHEAD;
    const size_t qrow0 = (size_t)b * S_LEN + qbase;
    const int kvbase = half * (S_LEN / 2);

    __shared__ __align__(16) u16 smem[17664];
    #define KS_OFF(buf) ((buf) * 4096)
    #define VS_OFF(buf) (8192 + (buf) * 4096)

    // staging: one chunk per thread (512 chunks per 64x64 tile)
    const int srow = tid >> 3;
    const int scg  = (tid & 7) ^ (srow & 7);
    const size_t ksrc = ((size_t)b * S_LEN + kvbase + srow) * D_MODEL + colbase + scg * 8;
    const size_t vsrc = (size_t)(colbase + srow) * NTOK + (size_t)b * S_LEN + kvbase + scg * 8;

    #define STAGE_KV(buf, kv0)                                                         \
        do {                                                                           \
            __builtin_amdgcn_global_load_lds(GAS(kw + ksrc + (size_t)(kv0) * D_MODEL), \
                                             LAS(smem + KS_OFF(buf) + wave * 512), 16, 0, 0); \
            __builtin_amdgcn_global_load_lds(GAS(vtw + vsrc + (kv0)),                  \
                                             LAS(smem + VS_OFF(buf) + wave * 512), 16, 0, 0); \
        } while (0)

    // Q B-frags, register-resident: B[k=d=16s+8hh+j][n=q=l31]
    bf16x8 qf[4];
    {
        const u16* qptr = qw + (qrow0 + wq * 32 + l31) * D_MODEL + colbase + hh * 8;
        #pragma unroll
        for (int s = 0; s < 4; ++s) qf[s] = *(const bf16x8*)(qptr + s * 16);
    }

    STAGE_KV(0, 0);

    f32x16 o[2];
    #pragma unroll
    for (int dt = 0; dt < 2; ++dt)
        #pragma unroll
        for (int r = 0; r < 16; ++r) o[dt][r] = 0.f;
    float l = 0.f;

    __syncthreads();

    for (int t = 0; t < S_LEN / 128; ++t) {   // 16 kv tiles of 64 per half
        const int cur = t & 1;
        if (t + 1 < S_LEN / 128) STAGE_KV(!cur, (t + 1) * 64);   // prefetch in flight

        // S^T (this wave's 32 kv rows x 32 q cols), C init -12 (exp2 headroom)
        f32x16 sc;
        #pragma unroll
        for (int r = 0; r < 16; ++r) sc[r] = -12.f;
        #pragma unroll
        for (int s = 0; s < 4; ++s) {
            bf16x8 kf = *(const bf16x8*)&smem[KS_OFF(cur) + SWZ8(wk * 32 + l31, s * 2 + hh)];
            sc = __builtin_amdgcn_mfma_f32_32x32x16_bf16(kf, qf[s], sc, 0, 0, 0);
        }

        // p = exp2(s); x[g] covers kv_local = 8g + 4hh + {0..3}
        unsigned x[4][2], y[4][2];
        #pragma unroll
        for (int g = 0; g < 4; ++g) {
            float p0 = __builtin_amdgcn_exp2f(sc[4 * g + 0]);
            float p1 = __builtin_amdgcn_exp2f(sc[4 * g + 1]);
            float p2 = __builtin_amdgcn_exp2f(sc[4 * g + 2]);
            float p3 = __builtin_amdgcn_exp2f(sc[4 * g + 3]);
            l += (p0 + p1) + (p2 + p3);
            x[g][0] = pack2bf(p0, p1);
            x[g][1] = pack2bf(p2, p3);
        }
        #pragma unroll
        for (int g = 0; g < 4; ++g) {
            y[g][0] = __shfl_xor((int)x[g][0], 32);
            y[g][1] = __shfl_xor((int)x[g][1], 32);
        }

        // PV: B-frag(sp) covers kv_local = 16sp + 8hh + j
        #pragma unroll
        for (int sp = 0; sp < 2; ++sp) {
            const int ge = 2 * sp, go = 2 * sp + 1;
            union { unsigned u[4]; bf16x8 v; } pf;
            pf.u[0] = hh ? y[go][0] : x[ge][0];
            pf.u[1] = hh ? y[go][1] : x[ge][1];
            pf.u[2] = hh ? x[go][0] : y[ge][0];
            pf.u[3] = hh ? x[go][1] : y[ge][1];
            #pragma unroll
            for (int dt = 0; dt < 2; ++dt) {
                bf16x8 vf = *(const bf16x8*)&smem[VS_OFF(cur) + SWZ8(dt * 32 + l31, wk * 4 + sp * 2 + hh)];
                o[dt] = __builtin_amdgcn_mfma_f32_32x32x16_bf16(vf, pf.v, o[dt], 0, 0, 0);
            }
        }

        __syncthreads();   // drains prefetch + protects both staging buffers
    }

    // merge lane halves of l (each covers complementary kv groups)
    l += __shfl_xor(l, 32);

    // cross kv-wave reduction through LDS (staging region dead now)
    float* Ored = (float*)smem;                   // [4 qt][32 q][68] f32
    float* Lred = (float*)(smem + 17408);         // [4 qt][32 q] f32
    float* opd = Ored + ((size_t)wq * 32 + l31) * 68;
    if (wk == 1) {
        #pragma unroll
        for (int dt = 0; dt < 2; ++dt)
            #pragma unroll
            for (int g = 0; g < 4; ++g)
                *(f32x4*)(opd + dt * 32 + 8 * g + 4 * hh) =
                    (f32x4){o[dt][4 * g + 0], o[dt][4 * g + 1], o[dt][4 * g + 2], o[dt][4 * g + 3]};
        if (hh == 0) Lred[wq * 32 + l31] = l;
    }
    __syncthreads();
    if (wk == 0) {
        l += Lred[wq * 32 + l31];
        int q = qbase + wq * 32 + l31;
        if (hh == 0) lp[((size_t)half * NHEAD + h) * NTOK + b * S_LEN + q] = l;
        // write UNNORMALIZED partial O (bf16) for this kv half
        size_t orow = ((size_t)half * NTOK + qrow0 + wq * 32 + l31) * D_MODEL + colbase;
        #pragma unroll
        for (int dt = 0; dt < 2; ++dt)
            #pragma unroll
            for (int g = 0; g < 4; ++g) {
                f32x4 add = *(const f32x4*)(opd + dt * 32 + 8 * g + 4 * hh);
                float v0 = o[dt][4 * g + 0] + add[0];
                float v1 = o[dt][4 * g + 1] + add[1];
                float v2 = o[dt][4 * g + 2] + add[2];
                float v3 = o[dt][4 * g + 3] + add[3];
                *(u32x2*)(op + orow + dt * 32 + 8 * g + 4 * hh) =
                    (u32x2){pack2bf(v0, v1), pack2bf(v2, v3)};
            }
    }
    #undef STAGE_KV
    #undef KS_OFF
    #undef VS_OFF
}

// ---------------------------------------------------------------------------
// merge: aw[tok][dm] = (O0 + O1) / (l0 + l1). 4M elements, 4 per thread.
// ---------------------------------------------------------------------------
__global__ __launch_bounds__(256) void merge_kernel(
    const u16* __restrict__ op, const float* __restrict__ lp, u16* __restrict__ aw)
{
    int idx = blockIdx.x * 256 + threadIdx.x;   // 1M threads
    int tok = idx >> 8;
    int dm  = (idx & 255) * 4;
    int h   = dm >> 6;
    size_t o0 = (size_t)tok * D_MODEL + dm;
    u32x2 a = *(const u32x2*)(op + o0);
    u32x2 c = *(const u32x2*)(op + (size_t)NTOK * D_MODEL + o0);
    float l0 = lp[(size_t)h * NTOK + tok];
    float l1 = lp[(size_t)(NHEAD + h) * NTOK + tok];
    float inv = 1.0f / (l0 + l1);
    float v0 = (__uint_as_float(a[0] << 16) + __uint_as_float(c[0] << 16)) * inv;
    float v1 = (__uint_as_float(a[0] & 0xFFFF0000u) + __uint_as_float(c[0] & 0xFFFF0000u)) * inv;
    float v2 = (__uint_as_float(a[1] << 16) + __uint_as_float(c[1] << 16)) * inv;
    float v3 = (__uint_as_float(a[1] & 0xFFFF0000u) + __uint_as_float(c[1] & 0xFFFF0000u)) * inv;
    *(u32x2*)(aw + o0) = (u32x2){pack2bf(v0, v1), pack2bf(v2, v3)};
}

// ---------------------------------------------------------------------------
// outproj: out[tok][dm] = aw @ Wo^T + bo (fp32 out). Operand-swapped
// (A=Wo m=dout, B=aw n=tok) -> float4 epilogue stores. Tile 128(dout)x64(tok).
// ---------------------------------------------------------------------------
__global__ __launch_bounds__(256) void outproj_kernel(
    const u16* __restrict__ aw, const u16* __restrict__ Wob,
    const float* __restrict__ bo, float* __restrict__ out)
{
    const int nbase = blockIdx.x * 64;    // token
    const int mbase = blockIdx.y * 128;   // dout
    const int tid = threadIdx.x, lane = tid & 63, wave = tid >> 6;
    const int m16 = lane & 15, quad = lane >> 4;
    const int wm = wave >> 1, wn = wave & 1;

    __shared__ __align__(16) u16 As[128 * 64];  // Wo tile
    __shared__ __align__(16) u16 Bs[64 * 64];   // aw tile

    int arow[4], acg[4], brow[2], bcg[2];
    #pragma unroll
    for (int c = 0; c < 4; ++c) {
        int p = (wave * 4 + c) * 64 + lane;
        arow[c] = p >> 3; acg[c] = (p & 7) ^ (arow[c] & 7);
    }
    #pragma unroll
    for (int c = 0; c < 2; ++c) {
        int p = (wave * 2 + c) * 64 + lane;
        brow[c] = p >> 3; bcg[c] = (p & 7) ^ (brow[c] & 7);
    }

    f32x4 acc[4][2];
    #pragma unroll
    for (int mt = 0; mt < 4; ++mt)
        #pragma unroll
        for (int nt = 0; nt < 2; ++nt) acc[mt][nt] = (f32x4){0.f, 0.f, 0.f, 0.f};

    for (int kc = 0; kc < D_MODEL; kc += 64) {
        #pragma unroll
        for (int c = 0; c < 4; ++c)
            __builtin_amdgcn_global_load_lds(
                GAS(Wob + (size_t)(mbase + arow[c]) * D_MODEL + kc + acg[c] * 8),
                LAS(As + (wave * 4 + c) * 512), 16, 0, 0);
        #pragma unroll
        for (int c = 0; c < 2; ++c)
            __builtin_amdgcn_global_load_lds(
                GAS(aw + (size_t)(nbase + brow[c]) * D_MODEL + kc + bcg[c] * 8),
                LAS(Bs + (wave * 2 + c) * 512), 16, 0, 0);
        __syncthreads();
        #pragma unroll
        for (int half = 0; half < 2; ++half) {
            bf16x8 af[4], bfr[2];
            #pragma unroll
            for (int mt = 0; mt < 4; ++mt)
                af[mt] = *(const bf16x8*)&As[SWZ8(wm * 64 + mt * 16 + m16, quad + 4 * half)];
            #pragma unroll
            for (int nt = 0; nt < 2; ++nt)
                bfr[nt] = *(const bf16x8*)&Bs[SWZ8(wn * 32 + nt * 16 + m16, quad + 4 * half)];
            #pragma unroll
            for (int mt = 0; mt < 4; ++mt)
                #pragma unroll
                for (int nt = 0; nt < 2; ++nt)
                    acc[mt][nt] = __builtin_amdgcn_mfma_f32_16x16x32_bf16(af[mt], bfr[nt], acc[mt][nt], 0, 0, 0);
        }
        __syncthreads();
    }

    #pragma unroll
    for (int mt = 0; mt < 4; ++mt) {
        int d0 = mbase + wm * 64 + mt * 16 + quad * 4;
        float4 b4 = *(const float4*)&bo[d0];
        #pragma unroll
        for (int nt = 0; nt < 2; ++nt) {
            int tok = nbase + wn * 32 + nt * 16 + m16;
            float4 st;
            st.x = acc[mt][nt][0] + b4.x;
            st.y = acc[mt][nt][1] + b4.y;
            st.z = acc[mt][nt][2] + b4.z;
            st.w = acc[mt][nt][3] + b4.w;
            *(float4*)(out + (size_t)tok * D_MODEL + d0) = st;
        }
    }
}

extern "C" void kernel_launch(void* const* d_in, const int* in_sizes, int n_in,
                              void* d_out, int out_size, void* d_ws, size_t ws_size,
                              hipStream_t stream) {
    const float* Q  = (const float*)d_in[0];
    const float* K  = (const float*)d_in[1];
    const float* V  = (const float*)d_in[2];
    const float* Wq = (const float*)d_in[3];
    const float* bq = (const float*)d_in[4];
    const float* Wk = (const float*)d_in[5];
    const float* bk = (const float*)d_in[6];
    const float* Wv = (const float*)d_in[7];
    const float* bv = (const float*)d_in[8];
    const float* Wo = (const float*)d_in[9];
    const float* bo = (const float*)d_in[10];

    const size_t NT = (size_t)NTOK * D_MODEL;    // 4M
    const size_t WN = (size_t)D_MODEL * D_MODEL; // 1M
    u16* base = (u16*)d_ws;                      // 28M u16 = 56 MB total
    u16* qw  = base;
    u16* kw  = base + NT;
    u16* vtw = base + 2 * NT;   // [1024 dout][4096 tok]
    u16* Qb  = base + 3 * NT;   // aliased by aww after proj
    u16* Kb  = base + 4 * NT;   // aliased by O-partials (2 x NT, Kb+Vb) after proj
    u16* Vb  = base + 5 * NT;
    u16* Wqb = base + 6 * NT;   // aliased by l-partials after proj
    u16* Wkb = Wqb + WN;
    u16* Wvb = Wkb + WN;
    u16* Wob = Wvb + WN;
    u16* aww = Qb;              // Qb dead after proj
    u16* opart = Kb;            // [2 halves][NTOK][D_MODEL] bf16 unnormalized
    float* lpart = (float*)Wqb; // [2 halves][NHEAD][NTOK] f32

    convert_kernel<<<1024, 256, 0, stream>>>(Q, K, V, Wq, Wk, Wv, Wo,
                                             Qb, Kb, Vb, Wqb, Wkb, Wvb, Wob);
    proj_kernel<<<dim3(256, 1, 3), 256, 0, stream>>>(Qb, Kb, Vb, Wqb, Wkb, Wvb,
                                                     bq, bk, bv, qw, kw, vtw);
    attn_kernel<<<dim3(S_LEN / 128, NHEAD, BATCH * 2), 512, 0, stream>>>(
        qw, kw, vtw, opart, lpart);
    merge_kernel<<<(NTOK * D_MODEL / 4) / 256, 256, 0, stream>>>(opart, lpart, aww);
    outproj_kernel<<<dim3(NTOK / 64, D_MODEL / 128), 256, 0, stream>>>(
        aww, Wob, bo, (float*)d_out);
}